// Round 2
// baseline (327.388 us; speedup 1.0000x reference)
//
#include <hip/hip_runtime.h>
#include <hip/hip_cooperative_groups.h>

namespace cg = cooperative_groups;

// Problem constants (B=64, L=512, H=1024)
constexpr int BB = 64;
constexpr int LL = 512;
constexpr int HH = 1024;
constexpr int SPLITS = 16;            // split-K factor for all GEMMs
constexpr int GRID  = 512;            // cooperative grid: 2 blocks/CU
constexpr int NTHR  = 256;
constexpr int NWORK_GEMM = 3 * 16 * SPLITS;   // 768 (r, n-tile, split) tiles

typedef float nt_float4 __attribute__((ext_vector_type(4)));

struct Args {
    const float* hs; const float* ho; const float* ha; const float* enc;
    const int* Fp;
    const float* W_as;  const float* W_so;  const float* W_oa;
    const float* Win_as; const float* Win_so; const float* Win_oa;
    const float* Wout_as; const float* Wout_so; const float* Wout_oa;
    float* part; float* hx; float* tt; float* wc; float* opm; float* ms;
    float* out;
};

// ---------------------------------------------------------------------------
// One (r, n-tile, split) tile of the skinny GEMM (verbatim from the verified
// 8-kernel version). smem: As[32][64] + Ws[32][64] = 16 KB.
// ---------------------------------------------------------------------------
template<int K0, int K1>
__device__ __forceinline__ void gemm_tile(const float* __restrict__ a0,
                                          const float* __restrict__ a1,
                                          const float* __restrict__ w,
                                          float* __restrict__ part_r,
                                          int nt, int sp, int tid,
                                          float (*As)[64], float (*Ws)[64])
{
    constexpr int K = K0 + K1;
    constexpr int KRANGE = K / SPLITS;
    const int n0 = nt << 6;
    const int ks = sp * KRANGE;
    const int tn = tid & 15;   // n quad index
    const int tm = tid >> 4;   // m quad index

    float acc[4][4] = {};

    for (int kt = ks; kt < ks + KRANGE; kt += 32) {
        {
            const int m   = tid >> 2;          // 0..63
            const int kk0 = (tid & 3) << 3;    // 0,8,16,24
            const int kg  = kt + kk0;
            const float* src = (K1 == 0 || kg < K0) ? (a0 + (size_t)m * HH + kg)
                                                    : (a1 + (size_t)m * HH + (kg - K0));
            float4 v0 = *(const float4*)(src);
            float4 v1 = *(const float4*)(src + 4);
            As[kk0 + 0][m] = v0.x; As[kk0 + 1][m] = v0.y;
            As[kk0 + 2][m] = v0.z; As[kk0 + 3][m] = v0.w;
            As[kk0 + 4][m] = v1.x; As[kk0 + 5][m] = v1.y;
            As[kk0 + 6][m] = v1.z; As[kk0 + 7][m] = v1.w;
        }
        {
            const int j4 = (tid & 15) << 2;
            int kk = tid >> 4;
            #pragma unroll
            for (int i = 0; i < 2; i++, kk += 16) {
                *(float4*)&Ws[kk][j4] = *(const float4*)(w + (size_t)(kt + kk) * HH + n0 + j4);
            }
        }
        __syncthreads();
        #pragma unroll
        for (int kk = 0; kk < 32; kk++) {
            float4 a4 = *(const float4*)&As[kk][tm << 2];
            float4 b4 = *(const float4*)&Ws[kk][tn << 2];
            float av[4] = {a4.x, a4.y, a4.z, a4.w};
            float bv[4] = {b4.x, b4.y, b4.z, b4.w};
            #pragma unroll
            for (int i = 0; i < 4; i++)
                #pragma unroll
                for (int j = 0; j < 4; j++)
                    acc[i][j] += av[i] * bv[j];
        }
        __syncthreads();
    }

    float* dst = part_r + (size_t)(sp << 6) * HH + n0 + (tn << 2);
    #pragma unroll
    for (int i = 0; i < 4; i++) {
        const int m = (tm << 2) + i;
        *(float4*)(dst + (size_t)m * HH) = make_float4(acc[i][0], acc[i][1], acc[i][2], acc[i][3]);
    }
}

// ---------------------------------------------------------------------------
// GEMM phase work decoders (wk = r*256 + sp*16 + nt).
// ---------------------------------------------------------------------------
__device__ __forceinline__ void gemmA_work(const Args& a, int wk, int tid,
                                           float (*As)[64], float (*Ws)[64])
{
    const int r  = wk >> 8;
    const int nt = wk & 15;
    const int sp = (wk >> 4) & 15;
    const float* a0 = (r == 0) ? a.ha : (r == 1) ? a.hs : a.ho;
    const float* a1 = (r == 0) ? a.hs : (r == 1) ? a.ho : a.ha;
    const float* w  = (r == 0) ? a.W_as : (r == 1) ? a.W_so : a.W_oa;
    gemm_tile<1024, 1024>(a0, a1, w, a.part + (size_t)r * SPLITS * 65536,
                          nt, sp, tid, As, Ws);
}

__device__ __forceinline__ void gemmC_work(const Args& a, int wk, int tid,
                                           float (*As)[64], float (*Ws)[64])
{
    const int r  = wk >> 8;
    const int nt = wk & 15;
    const int sp = (wk >> 4) & 15;
    const float* a0 = a.hx + (size_t)r * 65536;
    const float* w  = (r == 0) ? a.Win_as : (r == 1) ? a.Win_so : a.Win_oa;
    gemm_tile<1024, 0>(a0, nullptr, w, a.part + (size_t)r * SPLITS * 65536,
                       nt, sp, tid, As, Ws);
}

__device__ __forceinline__ void gemmG_work(const Args& a, int wk, int tid,
                                           float (*As)[64], float (*Ws)[64])
{
    const int r  = wk >> 8;
    const int nt = wk & 15;
    const int sp = (wk >> 4) & 15;
    const float* a0 = a.wc + (size_t)r * 65536;
    const float* a1 = a.hx + (size_t)r * 65536;
    const float* w  = (r == 0) ? a.Wout_as : (r == 1) ? a.Wout_so : a.Wout_oa;
    gemm_tile<1024, 1024>(a0, a1, w, a.part + (size_t)r * SPLITS * 65536,
                          nt, sp, tid, As, Ws);
}

// ---------------------------------------------------------------------------
// Sum SPLITS partials for one float4 slot, optional tanh. 49152 slots.
// ---------------------------------------------------------------------------
__device__ __forceinline__ void reduce_phase(const float* __restrict__ part,
                                             float* __restrict__ dst,
                                             int gtid, bool do_tanh)
{
    if (gtid >= 49152) return;
    const int flat = gtid << 2;
    const int r    = flat >> 16;
    const int mn   = flat & 65535;
    const float* p = part + (size_t)r * SPLITS * 65536 + mn;
    float4 s = *(const float4*)p;
    #pragma unroll
    for (int y = 1; y < SPLITS; y++) {
        float4 q = *(const float4*)(p + (size_t)y * 65536);
        s.x += q.x; s.y += q.y; s.z += q.z; s.w += q.w;
    }
    if (do_tanh) {
        s.x = tanhf(s.x); s.y = tanhf(s.y); s.z = tanhf(s.z); s.w = tanhf(s.w);
    }
    *(float4*)(dst + (size_t)r * 65536 + mn) = s;
}

// ---------------------------------------------------------------------------
// Flash attention chunk. LDS: o_l[4][1024] (16 KB) + ms_sh[4][3][2].
// Merge one relation at a time to keep LDS small (co-residency!).
// smem must be >= 4224 floats.
// ---------------------------------------------------------------------------
__device__ __forceinline__ void flash_phase(const Args& args, int chunk, int tid,
                                            float* smem)
{
    float (*o_l)[HH]     = (float(*)[HH])smem;            // [4][1024], 16 KB
    float (*ms_sh)[3][2] = (float(*)[3][2])(smem + 4096); // [4][3][2]
    const int b    = chunk >> 3;
    const int lc   = chunk & 7;
    const int lane = tid & 63;
    const int wv   = tid >> 6;

    // Target vectors in registers: tr[r][v] covers h = lane*4 + v*256.
    float4 tr[3][4];
    #pragma unroll
    for (int r = 0; r < 3; r++)
        #pragma unroll
        for (int v = 0; v < 4; v++)
            tr[r][v] = *(const float4*)&args.tt[(size_t)(r * BB + b) * HH + (lane << 2) + (v << 8)];

    float  m_run[3] = {-3.0e38f, -3.0e38f, -3.0e38f};
    float  S_run[3] = {0.f, 0.f, 0.f};
    float4 o_run[3][4];
    #pragma unroll
    for (int r = 0; r < 3; r++)
        #pragma unroll
        for (int v = 0; v < 4; v++)
            o_run[r][v] = make_float4(0.f, 0.f, 0.f, 0.f);

    const float* ebase = args.enc + ((size_t)b * LL + (lc << 6) + (wv << 2)) * HH + (lane << 2);

    for (int it = 0; it < 4; it++) {
        const float* e = ebase + (size_t)(it << 4) * HH;
        float4 ev[4][4];
        #pragma unroll
        for (int j = 0; j < 4; j++)
            #pragma unroll
            for (int v = 0; v < 4; v++)
                ev[j][v] = *(const float4*)(e + (size_t)j * HH + (v << 8));

        float s[3][4];
        #pragma unroll
        for (int j = 0; j < 4; j++) {
            float d0 = 0.f, d1 = 0.f, d2 = 0.f;
            #pragma unroll
            for (int v = 0; v < 4; v++) {
                const float4 x = ev[j][v];
                d0 += x.x * tr[0][v].x + x.y * tr[0][v].y + x.z * tr[0][v].z + x.w * tr[0][v].w;
                d1 += x.x * tr[1][v].x + x.y * tr[1][v].y + x.z * tr[1][v].z + x.w * tr[1][v].w;
                d2 += x.x * tr[2][v].x + x.y * tr[2][v].y + x.z * tr[2][v].z + x.w * tr[2][v].w;
            }
            #pragma unroll
            for (int off = 32; off > 0; off >>= 1) {
                d0 += __shfl_xor(d0, off);
                d1 += __shfl_xor(d1, off);
                d2 += __shfl_xor(d2, off);
            }
            s[0][j] = d0; s[1][j] = d1; s[2][j] = d2;
        }

        #pragma unroll
        for (int r = 0; r < 3; r++) {
            const float mb = fmaxf(fmaxf(s[r][0], s[r][1]), fmaxf(s[r][2], s[r][3]));
            const float mn_ = fmaxf(m_run[r], mb);
            const float alpha = __expf(m_run[r] - mn_);
            m_run[r] = mn_;
            float p[4];
            float psum = 0.f;
            #pragma unroll
            for (int j = 0; j < 4; j++) { p[j] = __expf(s[r][j] - mn_); psum += p[j]; }
            S_run[r] = S_run[r] * alpha + psum;
            #pragma unroll
            for (int v = 0; v < 4; v++) {
                float4 o = o_run[r][v];
                o.x *= alpha; o.y *= alpha; o.z *= alpha; o.w *= alpha;
                #pragma unroll
                for (int j = 0; j < 4; j++) {
                    const float4 x = ev[j][v];
                    o.x += p[j] * x.x; o.y += p[j] * x.y;
                    o.z += p[j] * x.z; o.w += p[j] * x.w;
                }
                o_run[r][v] = o;
            }
        }
    }

    // Stash per-wave (m, S) for all relations.
    if (lane == 0) {
        #pragma unroll
        for (int r = 0; r < 3; r++) { ms_sh[wv][r][0] = m_run[r]; ms_sh[wv][r][1] = S_run[r]; }
    }

    // Cross-wave merge, one relation at a time (16 KB LDS footprint).
    #pragma unroll
    for (int r = 0; r < 3; r++) {
        __syncthreads();   // prev-iteration reads done (and ms_sh visible at r=0)
        #pragma unroll
        for (int v = 0; v < 4; v++)
            *(float4*)&o_l[wv][(lane << 2) + (v << 8)] = o_run[r][v];
        __syncthreads();

        const float m0 = ms_sh[0][r][0], m1 = ms_sh[1][r][0];
        const float m2 = ms_sh[2][r][0], m3 = ms_sh[3][r][0];
        const float M = fmaxf(fmaxf(m0, m1), fmaxf(m2, m3));
        const float w0 = __expf(m0 - M), w1 = __expf(m1 - M);
        const float w2 = __expf(m2 - M), w3 = __expf(m3 - M);
        float4 q0 = *(const float4*)&o_l[0][tid << 2];
        float4 q1 = *(const float4*)&o_l[1][tid << 2];
        float4 q2 = *(const float4*)&o_l[2][tid << 2];
        float4 q3 = *(const float4*)&o_l[3][tid << 2];
        float4 acc;
        acc.x = w0 * q0.x + w1 * q1.x + w2 * q2.x + w3 * q3.x;
        acc.y = w0 * q0.y + w1 * q1.y + w2 * q2.y + w3 * q3.y;
        acc.z = w0 * q0.z + w1 * q1.z + w2 * q2.z + w3 * q3.z;
        acc.w = w0 * q0.w + w1 * q1.w + w2 * q2.w + w3 * q3.w;
        *(float4*)&args.opm[((size_t)chunk * 3 + r) * HH + (tid << 2)] = acc;
        if (tid == 0) {
            const float S = w0 * ms_sh[0][r][1] + w1 * ms_sh[1][r][1]
                          + w2 * ms_sh[2][r][1] + w3 * ms_sh[3][r][1];
            args.ms[((size_t)chunk * 3 + r) * 2 + 0] = M;
            args.ms[((size_t)chunk * 3 + r) * 2 + 1] = S;
        }
    }
}

// ---------------------------------------------------------------------------
// Combine 8 chunks per (b, r): LSE merge -> wc. LDS-free (redundant small
// loads hit L2). Thread owns h = tid*4.
// ---------------------------------------------------------------------------
__device__ __forceinline__ void combine_phase(const Args& args, int b, int r, int tid)
{
    float mv[8], sv[8];
    float M = -3.0e38f;
    #pragma unroll
    for (int c = 0; c < 8; c++) {
        const int chunk = (b << 3) + c;
        mv[c] = args.ms[((size_t)chunk * 3 + r) * 2 + 0];
        sv[c] = args.ms[((size_t)chunk * 3 + r) * 2 + 1];
        M = fmaxf(M, mv[c]);
    }
    float S = 0.f;
    float4 acc = make_float4(0.f, 0.f, 0.f, 0.f);
    #pragma unroll
    for (int c = 0; c < 8; c++) {
        const float wgt = __expf(mv[c] - M);
        S += wgt * sv[c];
        const int chunk = (b << 3) + c;
        float4 q = *(const float4*)&args.opm[((size_t)chunk * 3 + r) * HH + (tid << 2)];
        acc.x += wgt * q.x; acc.y += wgt * q.y;
        acc.z += wgt * q.z; acc.w += wgt * q.w;
    }
    const float inv = 1.0f / S;
    acc.x *= inv; acc.y *= inv; acc.z *= inv; acc.w *= inv;
    *(float4*)&args.wc[(size_t)(r * BB + b) * HH + (tid << 2)] = acc;
}

// ---------------------------------------------------------------------------
// Final reduce + tanh + broadcast F copies -> out[r][b][f][h]. gtid < 49152.
// ---------------------------------------------------------------------------
__device__ __forceinline__ void broadcast_phase(const Args& args, int gtid)
{
    const int flat = gtid << 2;
    const int r    = flat >> 16;
    const int mn   = flat & 65535;
    const float* p = args.part + (size_t)r * SPLITS * 65536 + mn;
    float4 s = *(const float4*)p;
    #pragma unroll
    for (int y = 1; y < SPLITS; y++) {
        float4 q = *(const float4*)(p + (size_t)y * 65536);
        s.x += q.x; s.y += q.y; s.z += q.z; s.w += q.w;
    }
    s.x = tanhf(s.x); s.y = tanhf(s.y); s.z = tanhf(s.z); s.w = tanhf(s.w);

    nt_float4 sv;
    sv.x = s.x; sv.y = s.y; sv.z = s.z; sv.w = s.w;

    const int F  = *args.Fp;
    const int bb = mn >> 10;
    const int hh = mn & 1023;
    float* o = args.out + ((size_t)(r * BB + bb) * F) * HH + hh;
    for (int f = 0; f < F; f++)
        __builtin_nontemporal_store(sv, (nt_float4*)(o + (size_t)f * HH));
}

// ---------------------------------------------------------------------------
// Cooperative mega-kernel: 8 phases, 7 grid.sync(). Block LDS = 16.9 KB so
// >= 3 blocks/CU even under a 64 KB LDS-cap occupancy model (512 co-resident
// blocks guaranteed).
// ---------------------------------------------------------------------------
__global__ __launch_bounds__(NTHR, 2)
void mega_kernel(Args args)
{
    __shared__ __align__(16) float smem[4224];   // 16.9 KB: union of all phases
    cg::grid_group grid = cg::this_grid();
    const int bid  = blockIdx.x;
    const int tid  = threadIdx.x;
    const int gtid = bid * NTHR + tid;

    float (*As)[64] = (float(*)[64])smem;          // gemm phases: 8 KB
    float (*Ws)[64] = (float(*)[64])(smem + 2048); //              8 KB

    for (int wk = bid; wk < NWORK_GEMM; wk += gridDim.x)
        gemmA_work(args, wk, tid, As, Ws);
    grid.sync();

    reduce_phase(args.part, args.hx, gtid, true);
    grid.sync();

    for (int wk = bid; wk < NWORK_GEMM; wk += gridDim.x)
        gemmC_work(args, wk, tid, As, Ws);
    grid.sync();

    reduce_phase(args.part, args.tt, gtid, false);
    grid.sync();

    flash_phase(args, bid, tid, smem);
    grid.sync();

    if (bid < 192)
        combine_phase(args, bid & 63, bid >> 6, tid);
    grid.sync();

    for (int wk = bid; wk < NWORK_GEMM; wk += gridDim.x)
        gemmG_work(args, wk, tid, As, Ws);
    grid.sync();

    if (gtid < 49152)
        broadcast_phase(args, gtid);
}

// ---------------------------------------------------------------------------
// Fallback: the proven 8-kernel chain (same device functions, thin wrappers).
// ---------------------------------------------------------------------------
__global__ __launch_bounds__(NTHR)
void k_gemmA(Args a)
{
    __shared__ __align__(16) float smem[4096];
    gemmA_work(a, blockIdx.x, threadIdx.x, (float(*)[64])smem, (float(*)[64])(smem + 2048));
}

__global__ __launch_bounds__(NTHR)
void k_gemmC(Args a)
{
    __shared__ __align__(16) float smem[4096];
    gemmC_work(a, blockIdx.x, threadIdx.x, (float(*)[64])smem, (float(*)[64])(smem + 2048));
}

__global__ __launch_bounds__(NTHR)
void k_gemmG(Args a)
{
    __shared__ __align__(16) float smem[4096];
    gemmG_work(a, blockIdx.x, threadIdx.x, (float(*)[64])smem, (float(*)[64])(smem + 2048));
}

__global__ __launch_bounds__(NTHR)
void k_reduceB(Args a) { reduce_phase(a.part, a.hx, blockIdx.x * NTHR + threadIdx.x, true); }

__global__ __launch_bounds__(NTHR)
void k_reduceD(Args a) { reduce_phase(a.part, a.tt, blockIdx.x * NTHR + threadIdx.x, false); }

__global__ __launch_bounds__(NTHR)
void k_flash(Args a)
{
    __shared__ __align__(16) float smem[4224];
    flash_phase(a, blockIdx.x, threadIdx.x, smem);
}

__global__ __launch_bounds__(NTHR)
void k_combine(Args a) { combine_phase(a, blockIdx.x, blockIdx.y, threadIdx.x); }

__global__ __launch_bounds__(NTHR)
void k_broadcast(Args a)
{
    const int gtid = blockIdx.x * NTHR + threadIdx.x;
    if (gtid < 49152) broadcast_phase(a, gtid);
}

// ---------------------------------------------------------------------------
extern "C" void kernel_launch(void* const* d_in, const int* in_sizes, int n_in,
                              void* d_out, int out_size, void* d_ws, size_t ws_size,
                              hipStream_t stream)
{
    (void)in_sizes; (void)n_in; (void)out_size; (void)ws_size;
    float* ws = (float*)d_ws;

    Args a;
    a.hs  = (const float*)d_in[0];
    a.ho  = (const float*)d_in[1];
    a.ha  = (const float*)d_in[2];
    a.enc = (const float*)d_in[3];
    a.Fp  = (const int*)d_in[4];
    a.W_as    = (const float*)d_in[5];
    a.W_so    = (const float*)d_in[6];
    a.W_oa    = (const float*)d_in[7];
    a.Win_as  = (const float*)d_in[8];
    a.Win_so  = (const float*)d_in[9];
    a.Win_oa  = (const float*)d_in[10];
    a.Wout_as = (const float*)d_in[11];
    a.Wout_so = (const float*)d_in[12];
    a.Wout_oa = (const float*)d_in[13];

    a.part = ws;                   // [3][16][64][1024] = 3,145,728 floats
    a.hx   = ws + 3145728;         // [3][64][1024]
    a.tt   = ws + 3342336;         // [3][64][1024]
    a.wc   = ws + 3538944;         // [3][64][1024]
    a.opm  = ws + 3735552;         // [512][3][1024] = 1,572,864 floats
    a.ms   = ws + 5308416;         // [512][3][2]
    a.out  = (float*)d_out;

    // One-time capability probe (host-side, capture-safe, no stream ops).
    static int coop = -2;
    if (coop == -2) {
        int dev = 0, cus = 0, nb = 0;
        hipGetDevice(&dev);
        hipDeviceGetAttribute(&cus, hipDeviceAttributeMultiprocessorCount, dev);
        hipError_t e = hipOccupancyMaxActiveBlocksPerMultiprocessor(&nb, mega_kernel, NTHR, 0);
        coop = (e == hipSuccess && nb > 0 && (long)nb * cus >= GRID) ? 1 : 0;
    }

    bool launched = false;
    if (coop == 1) {
        void* kargs[] = { (void*)&a };
        hipError_t e = hipLaunchCooperativeKernel((const void*)mega_kernel,
                                                  dim3(GRID), dim3(NTHR),
                                                  kargs, 0, stream);
        launched = (e == hipSuccess);
        if (!launched) coop = 0;   // don't retry the coop path next time
    }

    if (!launched) {
        k_gemmA<<<NWORK_GEMM, NTHR, 0, stream>>>(a);
        k_reduceB<<<192, NTHR, 0, stream>>>(a);
        k_gemmC<<<NWORK_GEMM, NTHR, 0, stream>>>(a);
        k_reduceD<<<192, NTHR, 0, stream>>>(a);
        k_flash<<<512, NTHR, 0, stream>>>(a);
        k_combine<<<dim3(64, 3), NTHR, 0, stream>>>(a);
        k_gemmG<<<NWORK_GEMM, NTHR, 0, stream>>>(a);
        k_broadcast<<<192, NTHR, 0, stream>>>(a);
    }
}